// Round 1
// baseline (207.210 us; speedup 1.0000x reference)
//
#include <hip/hip_runtime.h>
#include <stdint.h>

typedef __attribute__((ext_vector_type(4))) float f32x4;
typedef __attribute__((ext_vector_type(8))) short bf16x8;
typedef __attribute__((ext_vector_type(4))) short bf16x4;

#define MFMA16(a, b, c) __builtin_amdgcn_mfma_f32_16x16x32_bf16((a), (b), (c), 0, 0, 0)

__device__ __forceinline__ short f2bf(float f) {
    union { float f; uint32_t u; } v; v.f = f;
    uint32_t r = (v.u + 0x7fffu + ((v.u >> 16) & 1u)) >> 16;
    return (short)(uint16_t)r;
}

// ---------------------------------------------------------------------------
// GEMM: QKV = X[4096x1024] @ W[1024x3072] + bias, output bf16
// 128x128 tile, BK=32, 4 waves (2x2), reg-staged fp32->bf16, double-buffered
// ---------------------------------------------------------------------------
#define BM 128
#define BN 128
#define BK 32
#define KPAD 40  // padded LDS row length (elements); 80B = 5*16B keeps b128 alignment

__global__ __launch_bounds__(256, 2)
void gemm_qkv(const float* __restrict__ X, const float* __restrict__ W,
              const float* __restrict__ bias, short* __restrict__ QKV,
              const int M, const int N, const int K) {
    __shared__ short Asm[2][BM * KPAD];
    __shared__ short Bsm[2][BN * KPAD];

    const int tid  = threadIdx.x;
    const int lane = tid & 63;
    const int l15  = lane & 15;
    const int lq   = lane >> 4;
    const int wave = tid >> 6;
    const int wr = wave >> 1, wc = wave & 1;

    // XCD-aware swizzle (768 % 8 == 0 -> simple swizzle is bijective)
    const int nbn = N / BN;
    const int nwg = (M / BM) * nbn;
    const int cpx = nwg >> 3;
    const int bid = blockIdx.x;
    const int swz = (bid & 7) * cpx + (bid >> 3);
    const int m0 = (swz / nbn) * BM, n0 = (swz % nbn) * BN;

    // staging indices
    const int ar = tid >> 1, ac = (tid & 1) << 4;          // A: X[m0+ar][k0+ac..+15]
    const int bk4 = (tid & 7) << 2, bc4 = (tid >> 3) << 2; // B: W[k0+bk4+i][n0+bc4..+3]

    f32x4 acc[4][4];
#pragma unroll
    for (int m = 0; m < 4; ++m)
#pragma unroll
        for (int n = 0; n < 4; ++n) acc[m][n] = (f32x4)(0.0f);

    f32x4 areg[4], breg[4];

    auto stage_regs = [&](int k0) {
        const float* ap = X + (size_t)(m0 + ar) * K + k0 + ac;
#pragma unroll
        for (int i = 0; i < 4; ++i) areg[i] = *(const f32x4*)(ap + i * 4);
        const float* bp = W + (size_t)(k0 + bk4) * N + n0 + bc4;
#pragma unroll
        for (int i = 0; i < 4; ++i) breg[i] = *(const f32x4*)(bp + (size_t)i * N);
    };

    auto write_lds = [&](int bb) {
        bf16x8 ta0, ta1;
#pragma unroll
        for (int i = 0; i < 2; ++i)
#pragma unroll
            for (int j = 0; j < 4; ++j) ta0[i * 4 + j] = f2bf(areg[i][j]);
#pragma unroll
        for (int i = 0; i < 2; ++i)
#pragma unroll
            for (int j = 0; j < 4; ++j) ta1[i * 4 + j] = f2bf(areg[2 + i][j]);
        *(bf16x8*)&Asm[bb][ar * KPAD + ac]     = ta0;
        *(bf16x8*)&Asm[bb][ar * KPAD + ac + 8] = ta1;
        // B transposed into Bsm[c][k]
#pragma unroll
        for (int j = 0; j < 4; ++j) {
            bf16x4 tb;
            tb[0] = f2bf(breg[0][j]); tb[1] = f2bf(breg[1][j]);
            tb[2] = f2bf(breg[2][j]); tb[3] = f2bf(breg[3][j]);
            *(bf16x4*)&Bsm[bb][(bc4 + j) * KPAD + bk4] = tb;
        }
    };

    auto compute = [&](int bb) {
        bf16x8 af[4], bfv[4];
#pragma unroll
        for (int m = 0; m < 4; ++m)
            af[m] = *(const bf16x8*)&Asm[bb][(wr * 64 + m * 16 + l15) * KPAD + (lq << 3)];
#pragma unroll
        for (int n = 0; n < 4; ++n)
            bfv[n] = *(const bf16x8*)&Bsm[bb][(wc * 64 + n * 16 + l15) * KPAD + (lq << 3)];
#pragma unroll
        for (int m = 0; m < 4; ++m)
#pragma unroll
            for (int n = 0; n < 4; ++n) acc[m][n] = MFMA16(af[m], bfv[n], acc[m][n]);
    };

    const int nkt = K / BK;
    stage_regs(0);
    write_lds(0);
    __syncthreads();
    int cur = 0;
    for (int kt = 0; kt < nkt; ++kt) {
        if (kt + 1 < nkt) stage_regs((kt + 1) * BK);  // overlap with compute
        compute(cur);
        if (kt + 1 < nkt) {
            write_lds(cur ^ 1);
            __syncthreads();
            cur ^= 1;
        }
    }

    // epilogue: + bias, convert to bf16, store
    float bv[4];
#pragma unroll
    for (int n = 0; n < 4; ++n) bv[n] = bias[n0 + wc * 64 + n * 16 + l15];
#pragma unroll
    for (int m = 0; m < 4; ++m) {
        const int row = m0 + wr * 64 + m * 16 + (lq << 2);
#pragma unroll
        for (int n = 0; n < 4; ++n) {
            const int col = n0 + wc * 64 + n * 16 + l15;
#pragma unroll
            for (int r = 0; r < 4; ++r)
                QKV[(size_t)(row + r) * N + col] = f2bf(acc[m][n][r] + bv[n]);
        }
    }
}

// ---------------------------------------------------------------------------
// Causal flash attention over bf16 QKV [4096][3072]; head h cols = h*192+{0,64,128}
// grid (32 qtiles, 32 bh), 256 thr = 4 waves, wave owns 16 q-rows. Out fp32.
// ---------------------------------------------------------------------------
#define DPAD 72

__global__ __launch_bounds__(256, 2)
void attn_fwd(const short* __restrict__ QKV, float* __restrict__ Out) {
    __shared__ short Ksm[64 * DPAD];      // K[kv][d]
    __shared__ short Vsm[64 * DPAD];      // V^T[d][kv]
    __shared__ short Psm[4][16 * DPAD];   // per-wave P[q][kv]

    const int tid  = threadIdx.x;
    const int lane = tid & 63;
    const int l15  = lane & 15;
    const int lq   = lane >> 4;
    const int wave = tid >> 6;
    const int qt = blockIdx.x;   // 0..31
    const int bh = blockIdx.y;   // 0..31
    const int b = bh >> 4, h = bh & 15;
    const int q0 = qt * 64;

    const short* base = QKV + (size_t)b * 2048 * 3072 + h * 192;

    bf16x8 qf[2];
    {
        const short* qp = base + (size_t)(q0 + wave * 16 + l15) * 3072 + (lq << 3);
        qf[0] = *(const bf16x8*)qp;
        qf[1] = *(const bf16x8*)(qp + 32);
    }

    f32x4 o_acc[4];
#pragma unroll
    for (int n = 0; n < 4; ++n) o_acc[n] = (f32x4)(0.0f);
    float m_run[4] = {-1e30f, -1e30f, -1e30f, -1e30f};
    float l_run[4] = {0.f, 0.f, 0.f, 0.f};

    const float SCALE = 0.03125f;  // 1/sqrt(1024)

    const int kr = tid >> 3, kc = (tid & 7) << 3;            // K staging
    const int vr = tid & 31, vc = ((tid >> 5) & 7) << 3;     // V staging (transpose)

    const int ntiles = qt + 1;
    for (int t = 0; t < ntiles; ++t) {
        const int kv0 = t * 64;
        // stage K rows
#pragma unroll
        for (int p = 0; p < 2; ++p) {
            const int r = kr + p * 32;
            bf16x8 k8 = *(const bf16x8*)(base + (size_t)(kv0 + r) * 3072 + 64 + kc);
            *(bf16x8*)&Ksm[r * DPAD + kc] = k8;
        }
        // stage V transposed: Vsm[d][kv]
#pragma unroll
        for (int p = 0; p < 2; ++p) {
            const int r = vr + p * 32;
            bf16x8 v8 = *(const bf16x8*)(base + (size_t)(kv0 + r) * 3072 + 128 + vc);
#pragma unroll
            for (int j = 0; j < 8; ++j) Vsm[(vc + j) * DPAD + r] = v8[j];
        }
        __syncthreads();

        // QK^T: scores s[n][r] = S[q = lq*4+r][kv = n*16+l15]
        f32x4 s[4];
#pragma unroll
        for (int n = 0; n < 4; ++n) {
            const short* kp = &Ksm[(n * 16 + l15) * DPAD + (lq << 3)];
            bf16x8 k0 = *(const bf16x8*)kp;
            bf16x8 k1 = *(const bf16x8*)(kp + 32);
            f32x4 z = (f32x4)(0.0f);
            z = MFMA16(qf[0], k0, z);
            z = MFMA16(qf[1], k1, z);
            s[n] = z;
        }

        // scale + causal mask (only diagonal tile) + online softmax
        float sv[4][4];
        const int qg = q0 + wave * 16 + (lq << 2);
        const bool diag = (t == qt);
#pragma unroll
        for (int n = 0; n < 4; ++n) {
            const int kvg = kv0 + n * 16 + l15;
#pragma unroll
            for (int r = 0; r < 4; ++r) {
                float x = s[n][r] * SCALE;
                if (diag && kvg > qg + r) x = -1e30f;
                sv[n][r] = x;
            }
        }
        float mnew[4];
#pragma unroll
        for (int r = 0; r < 4; ++r)
            mnew[r] = fmaxf(fmaxf(sv[0][r], sv[1][r]), fmaxf(sv[2][r], sv[3][r]));
#pragma unroll
        for (int msk = 1; msk < 16; msk <<= 1)
#pragma unroll
            for (int r = 0; r < 4; ++r)
                mnew[r] = fmaxf(mnew[r], __shfl_xor(mnew[r], msk, 64));
#pragma unroll
        for (int r = 0; r < 4; ++r) mnew[r] = fmaxf(mnew[r], m_run[r]);

        float corr[4], psum[4];
#pragma unroll
        for (int r = 0; r < 4; ++r) {
            corr[r] = __expf(m_run[r] - mnew[r]);
            m_run[r] = mnew[r];
            psum[r] = 0.f;
        }
#pragma unroll
        for (int n = 0; n < 4; ++n)
#pragma unroll
            for (int r = 0; r < 4; ++r) {
                const float p = __expf(sv[n][r] - mnew[r]);
                psum[r] += p;
                Psm[wave][((lq << 2) + r) * DPAD + n * 16 + l15] = f2bf(p);
            }
#pragma unroll
        for (int msk = 1; msk < 16; msk <<= 1)
#pragma unroll
            for (int r = 0; r < 4; ++r) psum[r] += __shfl_xor(psum[r], msk, 64);
#pragma unroll
        for (int r = 0; r < 4; ++r) l_run[r] = l_run[r] * corr[r] + psum[r];
#pragma unroll
        for (int n = 0; n < 4; ++n)
#pragma unroll
            for (int r = 0; r < 4; ++r) o_acc[n][r] *= corr[r];

        // P fragments (same-wave LDS round-trip)
        bf16x8 pf[2];
        {
            const short* pp = &Psm[wave][l15 * DPAD + (lq << 3)];
            pf[0] = *(const bf16x8*)pp;
            pf[1] = *(const bf16x8*)(pp + 32);
        }
        // PV
#pragma unroll
        for (int n = 0; n < 4; ++n) {
            const short* vp = &Vsm[(n * 16 + l15) * DPAD + (lq << 3)];
            bf16x8 v0 = *(const bf16x8*)vp;
            bf16x8 v1 = *(const bf16x8*)(vp + 32);
            o_acc[n] = MFMA16(pf[0], v0, o_acc[n]);
            o_acc[n] = MFMA16(pf[1], v1, o_acc[n]);
        }
        __syncthreads();
    }

    // epilogue: Out is fp32 in [B,H,S,d] flat order (reference reshapes w/o permute)
#pragma unroll
    for (int r = 0; r < 4; ++r) {
        const float inv = 1.f / l_run[r];
        const size_t orow = ((size_t)(b * 16 + h) * 2048 + (q0 + wave * 16 + (lq << 2) + r)) * 64;
#pragma unroll
        for (int n = 0; n < 4; ++n) Out[orow + n * 16 + l15] = o_acc[n][r] * inv;
    }
}

extern "C" void kernel_launch(void* const* d_in, const int* in_sizes, int n_in,
                              void* d_out, int out_size, void* d_ws, size_t ws_size,
                              hipStream_t stream) {
    const float* x  = (const float*)d_in[0];
    const float* W0 = (const float*)d_in[1];
    const float* b0 = (const float*)d_in[2];
    float* out = (float*)d_out;
    short* qkv = (short*)d_ws;  // bf16 [4096][3072] = 25.2 MB

    const int M = 4096, N = 3072, K = 1024;
    gemm_qkv<<<dim3((M / BM) * (N / BN)), dim3(256), 0, stream>>>(x, W0, b0, qkv, M, N, K);
    attn_fwd<<<dim3(32, 32), dim3(256), 0, stream>>>(qkv, out);
}

// Round 2
// 164.050 us; speedup vs baseline: 1.2631x; 1.2631x over previous
//
#include <hip/hip_runtime.h>
#include <stdint.h>

typedef __attribute__((ext_vector_type(4))) float f32x4;
typedef __attribute__((ext_vector_type(8))) short bf16x8;
typedef __attribute__((ext_vector_type(4))) short bf16x4;

#define MFMA16(a, b, c) __builtin_amdgcn_mfma_f32_16x16x32_bf16((a), (b), (c), 0, 0, 0)

__device__ __forceinline__ short f2bf(float f) {
    union { float f; uint32_t u; } v; v.f = f;
    uint32_t r = (v.u + 0x7fffu + ((v.u >> 16) & 1u)) >> 16;
    return (short)(uint16_t)r;
}

// ---------------------------------------------------------------------------
// GEMM: QKV = X[4096x1024] @ W[1024x3072] + bias, output bf16  (unchanged R1)
// ---------------------------------------------------------------------------
#define BM 128
#define BN 128
#define BK 32
#define KPAD 40

__global__ __launch_bounds__(256, 2)
void gemm_qkv(const float* __restrict__ X, const float* __restrict__ W,
              const float* __restrict__ bias, short* __restrict__ QKV,
              const int M, const int N, const int K) {
    __shared__ short Asm[2][BM * KPAD];
    __shared__ short Bsm[2][BN * KPAD];

    const int tid  = threadIdx.x;
    const int lane = tid & 63;
    const int l15  = lane & 15;
    const int lq   = lane >> 4;
    const int wave = tid >> 6;
    const int wr = wave >> 1, wc = wave & 1;

    const int nbn = N / BN;
    const int nwg = (M / BM) * nbn;
    const int cpx = nwg >> 3;
    const int bid = blockIdx.x;
    const int swz = (bid & 7) * cpx + (bid >> 3);
    const int m0 = (swz / nbn) * BM, n0 = (swz % nbn) * BN;

    const int ar = tid >> 1, ac = (tid & 1) << 4;
    const int bk4 = (tid & 7) << 2, bc4 = (tid >> 3) << 2;

    f32x4 acc[4][4];
#pragma unroll
    for (int m = 0; m < 4; ++m)
#pragma unroll
        for (int n = 0; n < 4; ++n) acc[m][n] = (f32x4)(0.0f);

    f32x4 areg[4], breg[4];

    auto stage_regs = [&](int k0) {
        const float* ap = X + (size_t)(m0 + ar) * K + k0 + ac;
#pragma unroll
        for (int i = 0; i < 4; ++i) areg[i] = *(const f32x4*)(ap + i * 4);
        const float* bp = W + (size_t)(k0 + bk4) * N + n0 + bc4;
#pragma unroll
        for (int i = 0; i < 4; ++i) breg[i] = *(const f32x4*)(bp + (size_t)i * N);
    };

    auto write_lds = [&](int bb) {
        bf16x8 ta0, ta1;
#pragma unroll
        for (int i = 0; i < 2; ++i)
#pragma unroll
            for (int j = 0; j < 4; ++j) ta0[i * 4 + j] = f2bf(areg[i][j]);
#pragma unroll
        for (int i = 0; i < 2; ++i)
#pragma unroll
            for (int j = 0; j < 4; ++j) ta1[i * 4 + j] = f2bf(areg[2 + i][j]);
        *(bf16x8*)&Asm[bb][ar * KPAD + ac]     = ta0;
        *(bf16x8*)&Asm[bb][ar * KPAD + ac + 8] = ta1;
#pragma unroll
        for (int j = 0; j < 4; ++j) {
            bf16x4 tb;
            tb[0] = f2bf(breg[0][j]); tb[1] = f2bf(breg[1][j]);
            tb[2] = f2bf(breg[2][j]); tb[3] = f2bf(breg[3][j]);
            *(bf16x4*)&Bsm[bb][(bc4 + j) * KPAD + bk4] = tb;
        }
    };

    auto compute = [&](int bb) {
        bf16x8 af[4], bfv[4];
#pragma unroll
        for (int m = 0; m < 4; ++m)
            af[m] = *(const bf16x8*)&Asm[bb][(wr * 64 + m * 16 + l15) * KPAD + (lq << 3)];
#pragma unroll
        for (int n = 0; n < 4; ++n)
            bfv[n] = *(const bf16x8*)&Bsm[bb][(wc * 64 + n * 16 + l15) * KPAD + (lq << 3)];
#pragma unroll
        for (int m = 0; m < 4; ++m)
#pragma unroll
            for (int n = 0; n < 4; ++n) acc[m][n] = MFMA16(af[m], bfv[n], acc[m][n]);
    };

    const int nkt = K / BK;
    stage_regs(0);
    write_lds(0);
    __syncthreads();
    int cur = 0;
    for (int kt = 0; kt < nkt; ++kt) {
        if (kt + 1 < nkt) stage_regs((kt + 1) * BK);
        compute(cur);
        if (kt + 1 < nkt) {
            write_lds(cur ^ 1);
            __syncthreads();
            cur ^= 1;
        }
    }

    float bv[4];
#pragma unroll
    for (int n = 0; n < 4; ++n) bv[n] = bias[n0 + wc * 64 + n * 16 + l15];
#pragma unroll
    for (int m = 0; m < 4; ++m) {
        const int row = m0 + wr * 64 + m * 16 + (lq << 2);
#pragma unroll
        for (int n = 0; n < 4; ++n) {
            const int col = n0 + wc * 64 + n * 16 + l15;
#pragma unroll
            for (int r = 0; r < 4; ++r)
                QKV[(size_t)(row + r) * N + col] = f2bf(acc[m][n][r] + bv[n]);
        }
    }
}

// ---------------------------------------------------------------------------
// Causal flash attention v2: pair-balanced blocks (qt = {bx, 31-bx}),
// double-buffered K/V, async stage split, 1 barrier/tile, exp2-domain softmax.
// grid (16, 32), 256 thr = 4 waves, wave owns 16 q-rows. Out fp32 [B,H,S,d].
// ---------------------------------------------------------------------------
#define DPAD 72

__global__ __launch_bounds__(256, 2)
void attn_fwd(const short* __restrict__ QKV, float* __restrict__ Out) {
    __shared__ short Ksm[2][64 * DPAD];   // K[kv][d]
    __shared__ short Vsm[2][64 * DPAD];   // V^T[d][kv]
    __shared__ short Psm[4][16 * DPAD];   // per-wave P[q][kv]

    const int tid  = threadIdx.x;
    const int lane = tid & 63;
    const int l15  = lane & 15;
    const int lq   = lane >> 4;
    const int wave = tid >> 6;
    const int bh = blockIdx.y;
    const int b = bh >> 4, h = bh & 15;

    const short* base = QKV + (size_t)b * 2048 * 3072 + h * 192;

    // staging indices
    const int kr = tid >> 3, kc = (tid & 7) << 3;         // K rows
    const int vr = tid & 31, vc = ((tid >> 5) & 7) << 3;  // V transpose

    // scale folded with log2(e): softmax computed in exp2 domain
    const float SCALE2 = 0.03125f * 1.44269504f;

    bf16x8 kreg[2], vreg[2];

    auto load_tile_regs = [&](int kv0) {
#pragma unroll
        for (int p = 0; p < 2; ++p)
            kreg[p] = *(const bf16x8*)(base + (size_t)(kv0 + kr + p * 32) * 3072 + 64 + kc);
#pragma unroll
        for (int p = 0; p < 2; ++p)
            vreg[p] = *(const bf16x8*)(base + (size_t)(kv0 + vr + p * 32) * 3072 + 128 + vc);
    };

    auto write_tile_lds = [&](int bb) {
#pragma unroll
        for (int p = 0; p < 2; ++p)
            *(bf16x8*)&Ksm[bb][(kr + p * 32) * DPAD + kc] = kreg[p];
#pragma unroll
        for (int p = 0; p < 2; ++p) {
            const int r = vr + p * 32;
#pragma unroll
            for (int j = 0; j < 8; ++j) Vsm[bb][(vc + j) * DPAD + r] = vreg[p][j];
        }
    };

#pragma unroll 1
    for (int phase = 0; phase < 2; ++phase) {
        const int qt = (phase == 0) ? (int)blockIdx.x : 31 - (int)blockIdx.x;
        const int q0 = qt * 64;
        const int ntiles = qt + 1;

        bf16x8 qf[2];
        {
            const short* qp = base + (size_t)(q0 + wave * 16 + l15) * 3072 + (lq << 3);
            qf[0] = *(const bf16x8*)qp;
            qf[1] = *(const bf16x8*)(qp + 32);
        }

        f32x4 o_acc[4];
#pragma unroll
        for (int n = 0; n < 4; ++n) o_acc[n] = (f32x4)(0.0f);
        float m_run[4] = {-1e30f, -1e30f, -1e30f, -1e30f};
        float l_run[4] = {0.f, 0.f, 0.f, 0.f};

        // prologue: stage tile 0 into buf 0
        load_tile_regs(0);
        __syncthreads();          // protect bufs from previous phase's readers
        write_tile_lds(0);
        __syncthreads();
        int cur = 0;

#pragma unroll 1
        for (int t = 0; t < ntiles; ++t) {
            const bool haveNext = (t + 1 < ntiles);
            if (haveNext) load_tile_regs((t + 1) * 64);  // issue early, land late

            // ---- QK^T from Ksm[cur] ----
            f32x4 s[4];
#pragma unroll
            for (int n = 0; n < 4; ++n) {
                const short* kp = &Ksm[cur][(n * 16 + l15) * DPAD + (lq << 3)];
                bf16x8 k0 = *(const bf16x8*)kp;
                bf16x8 k1 = *(const bf16x8*)(kp + 32);
                f32x4 z = (f32x4)(0.0f);
                z = MFMA16(qf[0], k0, z);
                z = MFMA16(qf[1], k1, z);
                s[n] = z;
            }

            // ---- scale + causal mask + online softmax (exp2 domain) ----
            const int kv0 = t * 64;
            float sv[4][4];
            const int qg = q0 + wave * 16 + (lq << 2);
            const bool diag = (t == ntiles - 1);
#pragma unroll
            for (int n = 0; n < 4; ++n) {
                const int kvg = kv0 + n * 16 + l15;
#pragma unroll
                for (int r = 0; r < 4; ++r) {
                    float x = s[n][r] * SCALE2;
                    if (diag && kvg > qg + r) x = -1e30f;
                    sv[n][r] = x;
                }
            }
            float mnew[4];
#pragma unroll
            for (int r = 0; r < 4; ++r)
                mnew[r] = fmaxf(fmaxf(sv[0][r], sv[1][r]), fmaxf(sv[2][r], sv[3][r]));
#pragma unroll
            for (int msk = 1; msk < 16; msk <<= 1)
#pragma unroll
                for (int r = 0; r < 4; ++r)
                    mnew[r] = fmaxf(mnew[r], __shfl_xor(mnew[r], msk, 64));
#pragma unroll
            for (int r = 0; r < 4; ++r) mnew[r] = fmaxf(mnew[r], m_run[r]);

            float corr[4], psum[4];
#pragma unroll
            for (int r = 0; r < 4; ++r) {
                corr[r] = exp2f(m_run[r] - mnew[r]);
                m_run[r] = mnew[r];
                psum[r] = 0.f;
            }
#pragma unroll
            for (int n = 0; n < 4; ++n)
#pragma unroll
                for (int r = 0; r < 4; ++r) {
                    const float p = exp2f(sv[n][r] - mnew[r]);
                    psum[r] += p;
                    Psm[wave][((lq << 2) + r) * DPAD + n * 16 + l15] = f2bf(p);
                }
#pragma unroll
            for (int msk = 1; msk < 16; msk <<= 1)
#pragma unroll
                for (int r = 0; r < 4; ++r) psum[r] += __shfl_xor(psum[r], msk, 64);
#pragma unroll
            for (int r = 0; r < 4; ++r) l_run[r] = l_run[r] * corr[r] + psum[r];
#pragma unroll
            for (int n = 0; n < 4; ++n)
#pragma unroll
                for (int r = 0; r < 4; ++r) o_acc[n][r] *= corr[r];

            // ---- P fragments (same-wave LDS round trip) + PV from Vsm[cur] ----
            bf16x8 pf[2];
            {
                const short* pp = &Psm[wave][l15 * DPAD + (lq << 3)];
                pf[0] = *(const bf16x8*)pp;
                pf[1] = *(const bf16x8*)(pp + 32);
            }
#pragma unroll
            for (int n = 0; n < 4; ++n) {
                const short* vp = &Vsm[cur][(n * 16 + l15) * DPAD + (lq << 3)];
                bf16x8 v0 = *(const bf16x8*)vp;
                bf16x8 v1 = *(const bf16x8*)(vp + 32);
                o_acc[n] = MFMA16(pf[0], v0, o_acc[n]);
                o_acc[n] = MFMA16(pf[1], v1, o_acc[n]);
            }

            if (haveNext) {
                write_tile_lds(cur ^ 1);   // vmcnt drains here, not at compute
                __syncthreads();           // single barrier per tile
                cur ^= 1;
            }
        }

        // epilogue: fp32 out in [B,H,S,d] flat order
#pragma unroll
        for (int r = 0; r < 4; ++r) {
            const float inv = 1.f / l_run[r];
            const size_t orow =
                ((size_t)(b * 16 + h) * 2048 + (q0 + wave * 16 + (lq << 2) + r)) * 64;
#pragma unroll
            for (int n = 0; n < 4; ++n) Out[orow + n * 16 + l15] = o_acc[n][r] * inv;
        }
    }
}

extern "C" void kernel_launch(void* const* d_in, const int* in_sizes, int n_in,
                              void* d_out, int out_size, void* d_ws, size_t ws_size,
                              hipStream_t stream) {
    const float* x  = (const float*)d_in[0];
    const float* W0 = (const float*)d_in[1];
    const float* b0 = (const float*)d_in[2];
    float* out = (float*)d_out;
    short* qkv = (short*)d_ws;  // bf16 [4096][3072] = 25.2 MB

    const int M = 4096, N = 3072, K = 1024;
    gemm_qkv<<<dim3((M / BM) * (N / BN)), dim3(256), 0, stream>>>(x, W0, b0, qkv, M, N, K);
    attn_fwd<<<dim3(16, 32), dim3(256), 0, stream>>>(qkv, out);
}

// Round 3
// 148.954 us; speedup vs baseline: 1.3911x; 1.1014x over previous
//
#include <hip/hip_runtime.h>
#include <stdint.h>

typedef __attribute__((ext_vector_type(4))) float f32x4;
typedef __attribute__((ext_vector_type(8))) short bf16x8;
typedef __attribute__((ext_vector_type(4))) short bf16x4;

#define MFMA16(a, b, c) __builtin_amdgcn_mfma_f32_16x16x32_bf16((a), (b), (c), 0, 0, 0)

__device__ __forceinline__ short f2bf(float f) {
    union { float f; uint32_t u; } v; v.f = f;
    uint32_t r = (v.u + 0x7fffu + ((v.u >> 16) & 1u)) >> 16;
    return (short)(uint16_t)r;
}

// ---------------------------------------------------------------------------
// GEMM: QKV = X[4096x1024] @ W[1024x3072] + bias, output bf16  (unchanged)
// ---------------------------------------------------------------------------
#define BM 128
#define BN 128
#define BK 32
#define KPAD 40

__global__ __launch_bounds__(256, 2)
void gemm_qkv(const float* __restrict__ X, const float* __restrict__ W,
              const float* __restrict__ bias, short* __restrict__ QKV,
              const int M, const int N, const int K) {
    __shared__ short Asm[2][BM * KPAD];
    __shared__ short Bsm[2][BN * KPAD];

    const int tid  = threadIdx.x;
    const int lane = tid & 63;
    const int l15  = lane & 15;
    const int lq   = lane >> 4;
    const int wave = tid >> 6;
    const int wr = wave >> 1, wc = wave & 1;

    const int nbn = N / BN;
    const int nwg = (M / BM) * nbn;
    const int cpx = nwg >> 3;
    const int bid = blockIdx.x;
    const int swz = (bid & 7) * cpx + (bid >> 3);
    const int m0 = (swz / nbn) * BM, n0 = (swz % nbn) * BN;

    const int ar = tid >> 1, ac = (tid & 1) << 4;
    const int bk4 = (tid & 7) << 2, bc4 = (tid >> 3) << 2;

    f32x4 acc[4][4];
#pragma unroll
    for (int m = 0; m < 4; ++m)
#pragma unroll
        for (int n = 0; n < 4; ++n) acc[m][n] = (f32x4)(0.0f);

    f32x4 areg[4], breg[4];

    auto stage_regs = [&](int k0) {
        const float* ap = X + (size_t)(m0 + ar) * K + k0 + ac;
#pragma unroll
        for (int i = 0; i < 4; ++i) areg[i] = *(const f32x4*)(ap + i * 4);
        const float* bp = W + (size_t)(k0 + bk4) * N + n0 + bc4;
#pragma unroll
        for (int i = 0; i < 4; ++i) breg[i] = *(const f32x4*)(bp + (size_t)i * N);
    };

    auto write_lds = [&](int bb) {
        bf16x8 ta0, ta1;
#pragma unroll
        for (int i = 0; i < 2; ++i)
#pragma unroll
            for (int j = 0; j < 4; ++j) ta0[i * 4 + j] = f2bf(areg[i][j]);
#pragma unroll
        for (int i = 0; i < 2; ++i)
#pragma unroll
            for (int j = 0; j < 4; ++j) ta1[i * 4 + j] = f2bf(areg[2 + i][j]);
        *(bf16x8*)&Asm[bb][ar * KPAD + ac]     = ta0;
        *(bf16x8*)&Asm[bb][ar * KPAD + ac + 8] = ta1;
#pragma unroll
        for (int j = 0; j < 4; ++j) {
            bf16x4 tb;
            tb[0] = f2bf(breg[0][j]); tb[1] = f2bf(breg[1][j]);
            tb[2] = f2bf(breg[2][j]); tb[3] = f2bf(breg[3][j]);
            *(bf16x4*)&Bsm[bb][(bc4 + j) * KPAD + bk4] = tb;
        }
    };

    auto compute = [&](int bb) {
        bf16x8 af[4], bfv[4];
#pragma unroll
        for (int m = 0; m < 4; ++m)
            af[m] = *(const bf16x8*)&Asm[bb][(wr * 64 + m * 16 + l15) * KPAD + (lq << 3)];
#pragma unroll
        for (int n = 0; n < 4; ++n)
            bfv[n] = *(const bf16x8*)&Bsm[bb][(wc * 64 + n * 16 + l15) * KPAD + (lq << 3)];
#pragma unroll
        for (int m = 0; m < 4; ++m)
#pragma unroll
            for (int n = 0; n < 4; ++n) acc[m][n] = MFMA16(af[m], bfv[n], acc[m][n]);
    };

    const int nkt = K / BK;
    stage_regs(0);
    write_lds(0);
    __syncthreads();
    int cur = 0;
    for (int kt = 0; kt < nkt; ++kt) {
        if (kt + 1 < nkt) stage_regs((kt + 1) * BK);
        compute(cur);
        if (kt + 1 < nkt) {
            write_lds(cur ^ 1);
            __syncthreads();
            cur ^= 1;
        }
    }

    float bv[4];
#pragma unroll
    for (int n = 0; n < 4; ++n) bv[n] = bias[n0 + wc * 64 + n * 16 + l15];
#pragma unroll
    for (int m = 0; m < 4; ++m) {
        const int row = m0 + wr * 64 + m * 16 + (lq << 2);
#pragma unroll
        for (int n = 0; n < 4; ++n) {
            const int col = n0 + wc * 64 + n * 16 + l15;
#pragma unroll
            for (int r = 0; r < 4; ++r)
                QKV[(size_t)(row + r) * N + col] = f2bf(acc[m][n][r] + bv[n]);
        }
    }
}

// ---------------------------------------------------------------------------
// Causal flash attention v3: swapped QK^T (S^T = K·Q^T) -> in-register
// softmax (lane owns q-row), P packed via v_cvt_pk_bf16_f32 + ds_bpermute
// redistribution (no P LDS roundtrip). PV as O^T = V^T·P^T.
// grid (16, 32) pair-balanced, 256 thr = 4 waves, dbuf K/V. Out fp32 [B,H,S,d].
// ---------------------------------------------------------------------------
#define DPAD 72

__global__ __launch_bounds__(256, 2)
void attn_fwd(const short* __restrict__ QKV, float* __restrict__ Out) {
    __shared__ short Ksm[2][64 * DPAD];   // K[kv][d]
    __shared__ short Vsm[2][64 * DPAD];   // V^T[d][kv]

    const int tid  = threadIdx.x;
    const int lane = tid & 63;
    const int l15  = lane & 15;
    const int lq   = lane >> 4;
    const int wave = tid >> 6;
    const int bh = blockIdx.y;
    const int b = bh >> 4, h = bh & 15;

    const short* base = QKV + (size_t)b * 2048 * 3072 + h * 192;

    const int kr = tid >> 3, kc = (tid & 7) << 3;
    const int vr = tid & 31, vc = ((tid >> 5) & 7) << 3;

    const float SCALE2 = 0.03125f * 1.44269504f;  // 1/sqrt(1024) * log2(e)

    // bpermute byte-addresses for P redistribution (lane-constant)
    const int addrA = ((((2 * lq) & 3) << 4) + l15) << 2;      // j>>2 == 0 owners
    const int addrB = ((((2 * lq + 1) & 3) << 4) + l15) << 2;  // j>>2 == 1 owners
    const bool hi2 = (lq >> 1) != 0;

    bf16x8 kreg[2], vreg[2];

    auto load_tile_regs = [&](int kv0) {
#pragma unroll
        for (int p = 0; p < 2; ++p)
            kreg[p] = *(const bf16x8*)(base + (size_t)(kv0 + kr + p * 32) * 3072 + 64 + kc);
#pragma unroll
        for (int p = 0; p < 2; ++p)
            vreg[p] = *(const bf16x8*)(base + (size_t)(kv0 + vr + p * 32) * 3072 + 128 + vc);
    };

    auto write_tile_lds = [&](int bb) {
#pragma unroll
        for (int p = 0; p < 2; ++p)
            *(bf16x8*)&Ksm[bb][(kr + p * 32) * DPAD + kc] = kreg[p];
#pragma unroll
        for (int p = 0; p < 2; ++p) {
            const int r = vr + p * 32;
#pragma unroll
            for (int j = 0; j < 8; ++j) Vsm[bb][(vc + j) * DPAD + r] = vreg[p][j];
        }
    };

#pragma unroll 1
    for (int phase = 0; phase < 2; ++phase) {
        const int qt = (phase == 0) ? (int)blockIdx.x : 31 - (int)blockIdx.x;
        const int q0 = qt * 64;
        const int ntiles = qt + 1;

        bf16x8 qf[2];
        {
            const short* qp = base + (size_t)(q0 + wave * 16 + l15) * 3072 + (lq << 3);
            qf[0] = *(const bf16x8*)qp;
            qf[1] = *(const bf16x8*)(qp + 32);
        }

        f32x4 o[4];
#pragma unroll
        for (int n = 0; n < 4; ++n) o[n] = (f32x4)(0.0f);
        float m_run = -1e30f, l_run = 0.f;

        load_tile_regs(0);
        __syncthreads();
        write_tile_lds(0);
        __syncthreads();
        int cur = 0;

#pragma unroll 1
        for (int t = 0; t < ntiles; ++t) {
            const bool haveNext = (t + 1 < ntiles);
            if (haveNext) load_tile_regs((t + 1) * 64);

            // ---- swapped QK^T: S^T[kv][q], lane holds q=l15, kv=n*16+lq*4+r ----
            float p[4][4];
#pragma unroll
            for (int n = 0; n < 4; ++n) {
                const short* kp = &Ksm[cur][(n * 16 + l15) * DPAD + (lq << 3)];
                bf16x8 k0 = *(const bf16x8*)kp;
                bf16x8 k1 = *(const bf16x8*)(kp + 32);
                f32x4 z = (f32x4)(0.0f);
                z = MFMA16(k0, qf[0], z);
                z = MFMA16(k1, qf[1], z);
#pragma unroll
                for (int r = 0; r < 4; ++r) p[n][r] = z[r];
            }

            // ---- scale + causal mask (exp2 domain) ----
            const int kv0 = t * 64;
            const int qg = q0 + wave * 16 + l15;
            const bool diag = (t == ntiles - 1);
#pragma unroll
            for (int n = 0; n < 4; ++n)
#pragma unroll
                for (int r = 0; r < 4; ++r) {
                    float x = p[n][r] * SCALE2;
                    if (diag && (kv0 + n * 16 + (lq << 2) + r) > qg) x = -1e30f;
                    p[n][r] = x;
                }

            // ---- in-register online softmax (per-lane q-row) ----
            float mx = p[0][0];
#pragma unroll
            for (int n = 0; n < 4; ++n)
#pragma unroll
                for (int r = 0; r < 4; ++r) mx = fmaxf(mx, p[n][r]);
            mx = fmaxf(mx, __shfl_xor(mx, 16, 64));
            mx = fmaxf(mx, __shfl_xor(mx, 32, 64));
            const float mnew = fmaxf(m_run, mx);
            const float corr = exp2f(m_run - mnew);
            float ps = 0.f;
#pragma unroll
            for (int n = 0; n < 4; ++n)
#pragma unroll
                for (int r = 0; r < 4; ++r) {
                    p[n][r] = exp2f(p[n][r] - mnew);
                    ps += p[n][r];
                }
            ps += __shfl_xor(ps, 16, 64);
            ps += __shfl_xor(ps, 32, 64);
            l_run = l_run * corr + ps;
            m_run = mnew;
#pragma unroll
            for (int n = 0; n < 4; ++n) o[n] *= corr;

            // ---- pack P -> bf16 words w[n][v] (kv = n*16+lq*4+2v, +1) ----
            uint32_t wv[4][2];
#pragma unroll
            for (int n = 0; n < 4; ++n)
#pragma unroll
                for (int v = 0; v < 2; ++v)
                    asm("v_cvt_pk_bf16_f32 %0, %1, %2"
                        : "=v"(wv[n][v]) : "v"(p[n][2 * v]), "v"(p[n][2 * v + 1]));

            // ---- redistribute to x32 B-frag layout: pb[h][j] = P[32h+8lq+j][q] ----
            uint32_t W0[4], W1[4];
#pragma unroll
            for (int jw = 0; jw < 4; ++jw) {
                const int addr = (jw < 2) ? addrA : addrB;
                const int u = jw & 1;
                int f0 = __builtin_amdgcn_ds_bpermute(addr, (int)wv[0][u]);
                int f1 = __builtin_amdgcn_ds_bpermute(addr, (int)wv[1][u]);
                W0[jw] = hi2 ? (uint32_t)f1 : (uint32_t)f0;
                int g0 = __builtin_amdgcn_ds_bpermute(addr, (int)wv[2][u]);
                int g1 = __builtin_amdgcn_ds_bpermute(addr, (int)wv[3][u]);
                W1[jw] = hi2 ? (uint32_t)g1 : (uint32_t)g0;
            }
            union { uint32_t u[4]; bf16x8 v; } pb0, pb1;
#pragma unroll
            for (int i = 0; i < 4; ++i) { pb0.u[i] = W0[i]; pb1.u[i] = W1[i]; }

            // ---- PV: O^T[d][q] += V^T · P^T ----
#pragma unroll
            for (int n = 0; n < 4; ++n) {
                const short* vp = &Vsm[cur][(n * 16 + l15) * DPAD + (lq << 3)];
                bf16x8 v0 = *(const bf16x8*)vp;
                bf16x8 v1 = *(const bf16x8*)(vp + 32);
                o[n] = MFMA16(v0, pb0.v, o[n]);
                o[n] = MFMA16(v1, pb1.v, o[n]);
            }

            if (haveNext) {
                write_tile_lds(cur ^ 1);
                __syncthreads();
                cur ^= 1;
            }
        }

        // ---- epilogue: lane owns q-row q0+wave*16+l15, d = n*16+lq*4+r ----
        const float inv = 1.f / l_run;
        const size_t orow =
            ((size_t)(b * 16 + h) * 2048 + (q0 + wave * 16 + l15)) * 64;
#pragma unroll
        for (int n = 0; n < 4; ++n) {
            f32x4 ov = o[n] * inv;
            *(f32x4*)(Out + orow + n * 16 + (lq << 2)) = ov;
        }
    }
}

extern "C" void kernel_launch(void* const* d_in, const int* in_sizes, int n_in,
                              void* d_out, int out_size, void* d_ws, size_t ws_size,
                              hipStream_t stream) {
    const float* x  = (const float*)d_in[0];
    const float* W0 = (const float*)d_in[1];
    const float* b0 = (const float*)d_in[2];
    float* out = (float*)d_out;
    short* qkv = (short*)d_ws;  // bf16 [4096][3072] = 25.2 MB

    const int M = 4096, N = 3072, K = 1024;
    gemm_qkv<<<dim3((M / BM) * (N / BN)), dim3(256), 0, stream>>>(x, W0, b0, qkv, M, N, K);
    attn_fwd<<<dim3(16, 32), dim3(256), 0, stream>>>(qkv, out);
}

// Round 4
// 115.691 us; speedup vs baseline: 1.7911x; 1.2875x over previous
//
#include <hip/hip_runtime.h>
#include <stdint.h>

typedef __attribute__((ext_vector_type(4))) float f32x4;
typedef __attribute__((ext_vector_type(8))) short bf16x8;
typedef __attribute__((ext_vector_type(4))) short bf16x4;

#define MFMA16(a, b, c) __builtin_amdgcn_mfma_f32_16x16x32_bf16((a), (b), (c), 0, 0, 0)

__device__ __forceinline__ short f2bf(float f) {
    union { float f; uint32_t u; } v; v.f = f;
    uint32_t r = (v.u + 0x7fffu + ((v.u >> 16) & 1u)) >> 16;
    return (short)(uint16_t)r;
}

__device__ __forceinline__ void async_ld16(const short* g, short* l) {
    __builtin_amdgcn_global_load_lds(
        (const __attribute__((address_space(1))) uint32_t*)g,
        (__attribute__((address_space(3))) uint32_t*)l, 16, 0, 0);
}

// ---------------------------------------------------------------------------
// convert_x: X fp32 [4096*1024] -> bf16 (elementwise, 8/thread)
// ---------------------------------------------------------------------------
__global__ __launch_bounds__(256)
void convert_x(const float* __restrict__ X, short* __restrict__ Xb) {
    const int i8 = (blockIdx.x * 256 + threadIdx.x) << 3;
    f32x4 a = *(const f32x4*)(X + i8);
    f32x4 b = *(const f32x4*)(X + i8 + 4);
    bf16x8 o;
#pragma unroll
    for (int j = 0; j < 4; ++j) { o[j] = f2bf(a[j]); o[4 + j] = f2bf(b[j]); }
    *(bf16x8*)(Xb + i8) = o;
}

// ---------------------------------------------------------------------------
// convert_wt: W fp32 [1024][3072] -> Wt bf16 [3072][1024] (64x64 LDS transpose)
// ---------------------------------------------------------------------------
__global__ __launch_bounds__(256)
void convert_wt(const float* __restrict__ W, short* __restrict__ Wt) {
    __shared__ short T[64][72];  // row stride 144B = 9*16B -> b128-aligned reads
    const int t = threadIdx.x;
    const int n0 = blockIdx.x * 64, k0 = blockIdx.y * 64;
#pragma unroll
    for (int i = 0; i < 4; ++i) {
        const int r = i * 16 + (t >> 4);   // k
        const int c = (t & 15) << 2;       // n
        f32x4 v = *(const f32x4*)(W + (size_t)(k0 + r) * 3072 + n0 + c);
#pragma unroll
        for (int j = 0; j < 4; ++j) T[c + j][r] = f2bf(v[j]);
    }
    __syncthreads();
#pragma unroll
    for (int i = 0; i < 2; ++i) {
        const int r = i * 32 + (t >> 3);   // n
        const int c = (t & 7) << 3;        // k
        *(bf16x8*)(Wt + (size_t)(n0 + r) * 1024 + k0 + c) = *(const bf16x8*)&T[r][c];
    }
}

// ---------------------------------------------------------------------------
// gemm_bf16 (m97 structure): QKV = Xb[4096x1024] @ Wt^T[3072x1024] + bias
// 128x128 tile, BK=32, 4 waves 2x2, global_load_lds w=16, linear LDS,
// double-buffered, 1 barrier per K-step, XCD swizzle. Output bf16.
// ---------------------------------------------------------------------------
__global__ __launch_bounds__(256, 2)
void gemm_bf16(const short* __restrict__ Xb, const short* __restrict__ Wt,
               const float* __restrict__ bias, short* __restrict__ QKV) {
    __shared__ short Asm[2][128 * 32];
    __shared__ short Bsm[2][128 * 32];

    const int tid  = threadIdx.x;
    const int lane = tid & 63;
    const int l15  = lane & 15;
    const int lq   = lane >> 4;
    const int wave = tid >> 6;
    const int wr = wave >> 1, wc = wave & 1;

    const int bid = blockIdx.x;                    // 768 blocks, 768%8==0
    const int swz = (bid & 7) * 96 + (bid >> 3);
    const int m0 = (swz / 24) * 128, n0 = (swz % 24) * 128;

    const int srow = tid >> 2;          // staging row (plus issue*64)
    const int scol = (tid & 3) << 3;    // staging col (8 bf16 = 16B)

    f32x4 acc[4][4];
#pragma unroll
    for (int m = 0; m < 4; ++m)
#pragma unroll
        for (int n = 0; n < 4; ++n) acc[m][n] = (f32x4)(0.0f);

    auto stage = [&](int k0, int bb) {
#pragma unroll
        for (int i = 0; i < 2; ++i)
            async_ld16(Xb + (size_t)(m0 + i * 64 + srow) * 1024 + k0 + scol,
                       &Asm[bb][(i * 256 + wave * 64) * 8]);
#pragma unroll
        for (int i = 0; i < 2; ++i)
            async_ld16(Wt + (size_t)(n0 + i * 64 + srow) * 1024 + k0 + scol,
                       &Bsm[bb][(i * 256 + wave * 64) * 8]);
    };

    auto compute = [&](int bb) {
        bf16x8 af[4], bfv[4];
#pragma unroll
        for (int m = 0; m < 4; ++m)
            af[m] = *(const bf16x8*)&Asm[bb][(wr * 64 + m * 16 + l15) * 32 + (lq << 3)];
#pragma unroll
        for (int n = 0; n < 4; ++n)
            bfv[n] = *(const bf16x8*)&Bsm[bb][(wc * 64 + n * 16 + l15) * 32 + (lq << 3)];
#pragma unroll
        for (int m = 0; m < 4; ++m)
#pragma unroll
            for (int n = 0; n < 4; ++n) acc[m][n] = MFMA16(af[m], bfv[n], acc[m][n]);
    };

    stage(0, 0);
    __syncthreads();
    int cur = 0;
#pragma unroll 1
    for (int kt = 0; kt < 32; ++kt) {
        if (kt + 1 < 32) stage((kt + 1) * 32, cur ^ 1);
        compute(cur);
        __syncthreads();   // drains vmcnt (staged writes) + lgkm; protects buffers
        cur ^= 1;
    }

    float bv[4];
#pragma unroll
    for (int n = 0; n < 4; ++n) bv[n] = bias[n0 + wc * 64 + n * 16 + l15];
#pragma unroll
    for (int m = 0; m < 4; ++m) {
        const int row = m0 + wr * 64 + m * 16 + (lq << 2);
#pragma unroll
        for (int n = 0; n < 4; ++n) {
            const int col = n0 + wc * 64 + n * 16 + l15;
#pragma unroll
            for (int r = 0; r < 4; ++r)
                QKV[(size_t)(row + r) * 3072 + col] = f2bf(acc[m][n][r] + bv[n]);
        }
    }
}

// ---------------------------------------------------------------------------
// fallback GEMM (fp32 reg-staged) — used only if ws_size too small
// ---------------------------------------------------------------------------
#define BM 128
#define BN 128
#define BK 32
#define KPAD 40

__global__ __launch_bounds__(256, 2)
void gemm_qkv(const float* __restrict__ X, const float* __restrict__ W,
              const float* __restrict__ bias, short* __restrict__ QKV,
              const int M, const int N, const int K) {
    __shared__ short Asm[2][BM * KPAD];
    __shared__ short Bsm[2][BN * KPAD];

    const int tid  = threadIdx.x;
    const int lane = tid & 63;
    const int l15  = lane & 15;
    const int lq   = lane >> 4;
    const int wave = tid >> 6;
    const int wr = wave >> 1, wc = wave & 1;

    const int nbn = N / BN;
    const int nwg = (M / BM) * nbn;
    const int cpx = nwg >> 3;
    const int bid = blockIdx.x;
    const int swz = (bid & 7) * cpx + (bid >> 3);
    const int m0 = (swz / nbn) * BM, n0 = (swz % nbn) * BN;

    const int ar = tid >> 1, ac = (tid & 1) << 4;
    const int bk4 = (tid & 7) << 2, bc4 = (tid >> 3) << 2;

    f32x4 acc[4][4];
#pragma unroll
    for (int m = 0; m < 4; ++m)
#pragma unroll
        for (int n = 0; n < 4; ++n) acc[m][n] = (f32x4)(0.0f);

    f32x4 areg[4], breg[4];

    auto stage_regs = [&](int k0) {
        const float* ap = X + (size_t)(m0 + ar) * K + k0 + ac;
#pragma unroll
        for (int i = 0; i < 4; ++i) areg[i] = *(const f32x4*)(ap + i * 4);
        const float* bp = W + (size_t)(k0 + bk4) * N + n0 + bc4;
#pragma unroll
        for (int i = 0; i < 4; ++i) breg[i] = *(const f32x4*)(bp + (size_t)i * N);
    };

    auto write_lds = [&](int bb) {
        bf16x8 ta0, ta1;
#pragma unroll
        for (int i = 0; i < 2; ++i)
#pragma unroll
            for (int j = 0; j < 4; ++j) ta0[i * 4 + j] = f2bf(areg[i][j]);
#pragma unroll
        for (int i = 0; i < 2; ++i)
#pragma unroll
            for (int j = 0; j < 4; ++j) ta1[i * 4 + j] = f2bf(areg[2 + i][j]);
        *(bf16x8*)&Asm[bb][ar * KPAD + ac]     = ta0;
        *(bf16x8*)&Asm[bb][ar * KPAD + ac + 8] = ta1;
#pragma unroll
        for (int j = 0; j < 4; ++j) {
            bf16x4 tb;
            tb[0] = f2bf(breg[0][j]); tb[1] = f2bf(breg[1][j]);
            tb[2] = f2bf(breg[2][j]); tb[3] = f2bf(breg[3][j]);
            *(bf16x4*)&Bsm[bb][(bc4 + j) * KPAD + bk4] = tb;
        }
    };

    auto compute = [&](int bb) {
        bf16x8 af[4], bfv[4];
#pragma unroll
        for (int m = 0; m < 4; ++m)
            af[m] = *(const bf16x8*)&Asm[bb][(wr * 64 + m * 16 + l15) * KPAD + (lq << 3)];
#pragma unroll
        for (int n = 0; n < 4; ++n)
            bfv[n] = *(const bf16x8*)&Bsm[bb][(wc * 64 + n * 16 + l15) * KPAD + (lq << 3)];
#pragma unroll
        for (int m = 0; m < 4; ++m)
#pragma unroll
            for (int n = 0; n < 4; ++n) acc[m][n] = MFMA16(af[m], bfv[n], acc[m][n]);
    };

    const int nkt = K / BK;
    stage_regs(0);
    write_lds(0);
    __syncthreads();
    int cur = 0;
    for (int kt = 0; kt < nkt; ++kt) {
        if (kt + 1 < nkt) stage_regs((kt + 1) * BK);
        compute(cur);
        if (kt + 1 < nkt) {
            write_lds(cur ^ 1);
            __syncthreads();
            cur ^= 1;
        }
    }

    float bv[4];
#pragma unroll
    for (int n = 0; n < 4; ++n) bv[n] = bias[n0 + wc * 64 + n * 16 + l15];
#pragma unroll
    for (int m = 0; m < 4; ++m) {
        const int row = m0 + wr * 64 + m * 16 + (lq << 2);
#pragma unroll
        for (int n = 0; n < 4; ++n) {
            const int col = n0 + wc * 64 + n * 16 + l15;
#pragma unroll
            for (int r = 0; r < 4; ++r)
                QKV[(size_t)(row + r) * N + col] = f2bf(acc[m][n][r] + bv[n]);
        }
    }
}

// ---------------------------------------------------------------------------
// Causal flash attention v3 (unchanged from R3): swapped QK^T, in-register
// softmax, cvt_pk + ds_bpermute P redistribution, PV as O^T = V^T·P^T.
// ---------------------------------------------------------------------------
#define DPAD 72

__global__ __launch_bounds__(256, 2)
void attn_fwd(const short* __restrict__ QKV, float* __restrict__ Out) {
    __shared__ short Ksm[2][64 * DPAD];
    __shared__ short Vsm[2][64 * DPAD];

    const int tid  = threadIdx.x;
    const int lane = tid & 63;
    const int l15  = lane & 15;
    const int lq   = lane >> 4;
    const int wave = tid >> 6;
    const int bh = blockIdx.y;
    const int b = bh >> 4, h = bh & 15;

    const short* base = QKV + (size_t)b * 2048 * 3072 + h * 192;

    const int kr = tid >> 3, kc = (tid & 7) << 3;
    const int vr = tid & 31, vc = ((tid >> 5) & 7) << 3;

    const float SCALE2 = 0.03125f * 1.44269504f;

    const int addrA = ((((2 * lq) & 3) << 4) + l15) << 2;
    const int addrB = ((((2 * lq + 1) & 3) << 4) + l15) << 2;
    const bool hi2 = (lq >> 1) != 0;

    bf16x8 kreg[2], vreg[2];

    auto load_tile_regs = [&](int kv0) {
#pragma unroll
        for (int p = 0; p < 2; ++p)
            kreg[p] = *(const bf16x8*)(base + (size_t)(kv0 + kr + p * 32) * 3072 + 64 + kc);
#pragma unroll
        for (int p = 0; p < 2; ++p)
            vreg[p] = *(const bf16x8*)(base + (size_t)(kv0 + vr + p * 32) * 3072 + 128 + vc);
    };

    auto write_tile_lds = [&](int bb) {
#pragma unroll
        for (int p = 0; p < 2; ++p)
            *(bf16x8*)&Ksm[bb][(kr + p * 32) * DPAD + kc] = kreg[p];
#pragma unroll
        for (int p = 0; p < 2; ++p) {
            const int r = vr + p * 32;
#pragma unroll
            for (int j = 0; j < 8; ++j) Vsm[bb][(vc + j) * DPAD + r] = vreg[p][j];
        }
    };

#pragma unroll 1
    for (int phase = 0; phase < 2; ++phase) {
        const int qt = (phase == 0) ? (int)blockIdx.x : 31 - (int)blockIdx.x;
        const int q0 = qt * 64;
        const int ntiles = qt + 1;

        bf16x8 qf[2];
        {
            const short* qp = base + (size_t)(q0 + wave * 16 + l15) * 3072 + (lq << 3);
            qf[0] = *(const bf16x8*)qp;
            qf[1] = *(const bf16x8*)(qp + 32);
        }

        f32x4 o[4];
#pragma unroll
        for (int n = 0; n < 4; ++n) o[n] = (f32x4)(0.0f);
        float m_run = -1e30f, l_run = 0.f;

        load_tile_regs(0);
        __syncthreads();
        write_tile_lds(0);
        __syncthreads();
        int cur = 0;

#pragma unroll 1
        for (int t = 0; t < ntiles; ++t) {
            const bool haveNext = (t + 1 < ntiles);
            if (haveNext) load_tile_regs((t + 1) * 64);

            float p[4][4];
#pragma unroll
            for (int n = 0; n < 4; ++n) {
                const short* kp = &Ksm[cur][(n * 16 + l15) * DPAD + (lq << 3)];
                bf16x8 k0 = *(const bf16x8*)kp;
                bf16x8 k1 = *(const bf16x8*)(kp + 32);
                f32x4 z = (f32x4)(0.0f);
                z = MFMA16(k0, qf[0], z);
                z = MFMA16(k1, qf[1], z);
#pragma unroll
                for (int r = 0; r < 4; ++r) p[n][r] = z[r];
            }

            const int kv0 = t * 64;
            const int qg = q0 + wave * 16 + l15;
            const bool diag = (t == ntiles - 1);
#pragma unroll
            for (int n = 0; n < 4; ++n)
#pragma unroll
                for (int r = 0; r < 4; ++r) {
                    float x = p[n][r] * SCALE2;
                    if (diag && (kv0 + n * 16 + (lq << 2) + r) > qg) x = -1e30f;
                    p[n][r] = x;
                }

            float mx = p[0][0];
#pragma unroll
            for (int n = 0; n < 4; ++n)
#pragma unroll
                for (int r = 0; r < 4; ++r) mx = fmaxf(mx, p[n][r]);
            mx = fmaxf(mx, __shfl_xor(mx, 16, 64));
            mx = fmaxf(mx, __shfl_xor(mx, 32, 64));
            const float mnew = fmaxf(m_run, mx);
            const float corr = exp2f(m_run - mnew);
            float ps = 0.f;
#pragma unroll
            for (int n = 0; n < 4; ++n)
#pragma unroll
                for (int r = 0; r < 4; ++r) {
                    p[n][r] = exp2f(p[n][r] - mnew);
                    ps += p[n][r];
                }
            ps += __shfl_xor(ps, 16, 64);
            ps += __shfl_xor(ps, 32, 64);
            l_run = l_run * corr + ps;
            m_run = mnew;
#pragma unroll
            for (int n = 0; n < 4; ++n) o[n] *= corr;

            uint32_t wv[4][2];
#pragma unroll
            for (int n = 0; n < 4; ++n)
#pragma unroll
                for (int v = 0; v < 2; ++v)
                    asm("v_cvt_pk_bf16_f32 %0, %1, %2"
                        : "=v"(wv[n][v]) : "v"(p[n][2 * v]), "v"(p[n][2 * v + 1]));

            uint32_t W0[4], W1[4];
#pragma unroll
            for (int jw = 0; jw < 4; ++jw) {
                const int addr = (jw < 2) ? addrA : addrB;
                const int u = jw & 1;
                int f0 = __builtin_amdgcn_ds_bpermute(addr, (int)wv[0][u]);
                int f1 = __builtin_amdgcn_ds_bpermute(addr, (int)wv[1][u]);
                W0[jw] = hi2 ? (uint32_t)f1 : (uint32_t)f0;
                int g0 = __builtin_amdgcn_ds_bpermute(addr, (int)wv[2][u]);
                int g1 = __builtin_amdgcn_ds_bpermute(addr, (int)wv[3][u]);
                W1[jw] = hi2 ? (uint32_t)g1 : (uint32_t)g0;
            }
            union { uint32_t u[4]; bf16x8 v; } pb0, pb1;
#pragma unroll
            for (int i = 0; i < 4; ++i) { pb0.u[i] = W0[i]; pb1.u[i] = W1[i]; }

#pragma unroll
            for (int n = 0; n < 4; ++n) {
                const short* vp = &Vsm[cur][(n * 16 + l15) * DPAD + (lq << 3)];
                bf16x8 v0 = *(const bf16x8*)vp;
                bf16x8 v1 = *(const bf16x8*)(vp + 32);
                o[n] = MFMA16(v0, pb0.v, o[n]);
                o[n] = MFMA16(v1, pb1.v, o[n]);
            }

            if (haveNext) {
                write_tile_lds(cur ^ 1);
                __syncthreads();
                cur ^= 1;
            }
        }

        const float inv = 1.f / l_run;
        const size_t orow =
            ((size_t)(b * 16 + h) * 2048 + (q0 + wave * 16 + l15)) * 64;
#pragma unroll
        for (int n = 0; n < 4; ++n) {
            f32x4 ov = o[n] * inv;
            *(f32x4*)(Out + orow + n * 16 + (lq << 2)) = ov;
        }
    }
}

extern "C" void kernel_launch(void* const* d_in, const int* in_sizes, int n_in,
                              void* d_out, int out_size, void* d_ws, size_t ws_size,
                              hipStream_t stream) {
    const float* x  = (const float*)d_in[0];
    const float* W0 = (const float*)d_in[1];
    const float* b0 = (const float*)d_in[2];
    float* out = (float*)d_out;
    char* ws = (char*)d_ws;

    const size_t QKV_B = (size_t)4096 * 3072 * 2;  // 25.2 MB
    const size_t XBF_B = (size_t)4096 * 1024 * 2;  // 8.4 MB
    const size_t WT_B  = (size_t)3072 * 1024 * 2;  // 6.3 MB

    short* qkv = (short*)ws;
    if (ws_size >= QKV_B + XBF_B + WT_B) {
        short* xb = (short*)(ws + QKV_B);
        short* wt = (short*)(ws + QKV_B + XBF_B);
        convert_x<<<dim3(2048), dim3(256), 0, stream>>>(x, xb);
        convert_wt<<<dim3(48, 16), dim3(256), 0, stream>>>(W0, wt);
        gemm_bf16<<<dim3(768), dim3(256), 0, stream>>>(xb, wt, b0, qkv);
    } else {
        gemm_qkv<<<dim3(768), dim3(256), 0, stream>>>(x, W0, b0, qkv, 4096, 3072, 1024);
    }
    attn_fwd<<<dim3(16, 32), dim3(256), 0, stream>>>(qkv, out);
}